// Round 6
// baseline (549.561 us; speedup 1.0000x reference)
//
#include <hip/hip_runtime.h>
#include <hip/hip_bf16.h>

// RNN wavefunction log-prob: N=128 steps, B=8192, H=128, D=2 (one-hot).
// R13: R7 base (proven 197us codegen: 8 waves, 16 rows/wave, VGPR=64+AGPR,
// 2 blocks/CU reg-capped) + two low-risk edits:
//  1) 4-way logit-duty split: waves {i,i+2,i+4,i+6}&7 each do ONE kb
//     (1 ds_read + 1 MFMA + partial-diff write; diff linear in partials,
//     summed in final pass). Kills the per-step barrier straggler.
//  2) s_setprio(1) around main MFMA cluster (2 independent blocks/CU at
//     different phases = attn-like regime, m191 +4-7%).
// Revert triggers: WRITE_SIZE >> 32KB (spill) or dur >= 195us (theory dead).

#define NSTEP 128
#define BTOT  8192
#define HID   128
#define MB    16
#define NBLK  (BTOT / MB)   // 512
#define NTHR  512

typedef __attribute__((ext_vector_type(8))) short bf16x8;
typedef __attribute__((ext_vector_type(4))) float f32x4;
typedef __attribute__((ext_vector_type(2))) float f32x2;
typedef __attribute__((ext_vector_type(2))) unsigned uint32x2;

__device__ __forceinline__ short f2bf(float v) {
    unsigned u = __builtin_bit_cast(unsigned, v);
    u += 0x7FFFu + ((u >> 16) & 1u);
    return (short)(u >> 16);
}
// two f32 -> packed bf16x2 via v_cvt_pk_bf16_f32
__device__ __forceinline__ unsigned cvt2bf(float a, float b) {
    __hip_bfloat162 h2 = __float22bfloat162_rn(make_float2(a, b));
    unsigned u; __builtin_memcpy(&u, &h2, sizeof(u));
    return u;
}
// tanh on a pair: 2 exp + ONE rcp (shared via rcp(d0*d1))
__device__ __forceinline__ f32x2 tanh2(f32x2 x) {
    f32x2 z = x * 2.885390081777927f;            // 2x*log2(e)
    float e0 = __builtin_exp2f(z.x);
    float e1 = __builtin_exp2f(z.y);
    f32x2 d = {e0 + 1.0f, e1 + 1.0f};
    float r = __builtin_amdgcn_rcpf(d.x * d.y);
    f32x2 inv = {r * d.y, r * d.x};              // 1/d.x, 1/d.y
    return inv * -2.0f + 1.0f;
}

__global__ __launch_bounds__(NTHR, 4) void rnn_wf_kernel(
    const float* __restrict__ samples,  // (128, 8192, 2)
    const float* __restrict__ Wih0,     // (128, 2)
    const float* __restrict__ bih0,     // (128,)
    const float* __restrict__ Whh0,     // (128, 128)
    const float* __restrict__ bhh0,     // (128,)
    const float* __restrict__ Wih1,     // (128, 128)
    const float* __restrict__ bih1,     // (128,)
    const float* __restrict__ Whh1,     // (128, 128)
    const float* __restrict__ bhh1,     // (128,)
    const float* __restrict__ Wd,       // (2, 128)
    const float* __restrict__ bd,       // (2,)
    float* __restrict__ out)            // (1, 8192)
{
    __shared__ short sH0[2][MB * HID];
    __shared__ short sH1[2][MB * HID];
    __shared__ unsigned sMask[NSTEP];
    __shared__ float sLd[NSTEP * 4 * 17];        // partial logit diffs [(t*4+k)*17 + s]
    __shared__ __attribute__((aligned(16))) float sBias[4 * HID];
    // segments: [0:128)=WA (b0+Wih0 col0), [128:256)=WB (col1),
    //           [256:384)=B1, [384:512)=B0 plain
    __shared__ __attribute__((aligned(16))) short sFwd[4 * 64 * 8];

    const int tid  = threadIdx.x;
    const int b0   = blockIdx.x * MB;
    const int w    = tid >> 6;          // wave 0..7, owns n in [16w, 16w+16)
    const int lane = tid & 63;
    const int q    = lane >> 4;
    const int c    = lane & 15;

    // ---- decode f32 one-hot samples -> per-step 16-bit masks ----
    if (tid < NSTEP) {
        unsigned msk = 0;
        #pragma unroll
        for (int m = 0; m < MB; ++m) {
            float e1 = samples[((size_t)tid * BTOT + b0 + m) * 2 + 1];
            if (e1 > 0.5f) msk |= (1u << m);
        }
        sMask[tid] = msk;
    }
    // ---- biases into LDS ----
    if (tid >= NSTEP && tid < NSTEP + HID) {
        const int n = tid - NSTEP;
        const float bb = bih0[n] + bhh0[n];
        sBias[n]       = bb + Wih0[n * 2 + 0];
        sBias[128 + n] = bb + Wih0[n * 2 + 1];
        sBias[256 + n] = bih1[n] + bhh1[n];
        sBias[384 + n] = bb;
    }
    // ---- dense-head fragments into LDS ----
    if (tid >= 256 && tid < 512) {
        const int t2 = tid - 256;
        const int kb = t2 >> 6, l = t2 & 63, cc = l & 15, qq = l >> 4;
        bf16x8 v;
        #pragma unroll
        for (int j = 0; j < 8; ++j)
            v[j] = (cc < 2) ? f2bf(Wd[cc * HID + kb * 32 + qq * 8 + j]) : (short)0;
        *reinterpret_cast<bf16x8*>(&sFwd[(kb * 64 + l) * 8]) = v;
    }

    // ---- weight A-fragments: lane holds W[16w+c][kb*32+q*8 .. +8] ----
    bf16x8 fhh0[4], fih1[4], fhh1[4];
    {
        const int nn = w * 16 + c;
        #pragma unroll
        for (int kb = 0; kb < 4; ++kb) {
            const int off = nn * HID + kb * 32 + q * 8;
            bf16x8 v0, v1, v2;
            #pragma unroll
            for (int j = 0; j < 8; ++j) {
                v0[j] = f2bf(Whh0[off + j]);
                v1[j] = f2bf(Wih1[off + j]);
                v2[j] = f2bf(Whh1[off + j]);
            }
            fhh0[kb] = v0; fih1[kb] = v1; fhh1[kb] = v2;
        }
    }
    const float bd0 = bd[0], bd1 = bd[1];

    // ---- t-invariant LDS indices ----
    int ra[4];
    #pragma unroll
    for (int kb = 0; kb < 4; ++kb)
        ra[kb] = c * HID + (((kb * 4 + q) ^ c) << 3);
    // write: h'[m=c][n = 16w + 4q + r]; 8-block = 2w + (q>>1), half q&1
    const int wa = c * HID + (((2 * w + (q >> 1)) ^ c) << 3) + ((q & 1) << 2);
    const int ib = w * 16 + q * 4;   // float index into bias arrays

    bool bmPrev = false;

    // write one layer's 4 tanh'd values (b64)
    auto storeL = [&](short* buf, const f32x4& a) {
        f32x2 t0 = tanh2((f32x2){a[0], a[1]});
        f32x2 t1 = tanh2((f32x2){a[2], a[3]});
        uint32x2 v = {cvt2bf(t0.x, t0.y), cvt2bf(t1.x, t1.y)};
        *reinterpret_cast<uint32x2*>(&buf[wa]) = v;
    };

    __syncthreads();                 // sMask, sBias, sFwd published

    // ---- i = 0: h0(0) = tanh(b0) ----
    storeL(sH0[1], *reinterpret_cast<const f32x4*>(&sBias[384 + ib]));
    __syncthreads();

    // ---- i = 1: h0(1), h1(0) ----
    {
        const bool bmIn = (sMask[0] >> c) & 1u;
        const float* bp = bmIn ? (sBias + 128) : sBias;
        f32x4 a0 = *reinterpret_cast<const f32x4*>(&bp[ib]);
        f32x4 a1 = *reinterpret_cast<const f32x4*>(&sBias[256 + ib]);
        #pragma unroll
        for (int kb = 0; kb < 4; ++kb) {
            bf16x8 f0 = *reinterpret_cast<const bf16x8*>(&sH0[1][ra[kb]]);
            a0 = __builtin_amdgcn_mfma_f32_16x16x32_bf16(fhh0[kb], f0, a0, 0, 0, 0);
            a1 = __builtin_amdgcn_mfma_f32_16x16x32_bf16(fih1[kb], f0, a1, 0, 0, 0);
        }
        storeL(sH0[0], a0);   // h0(1)
        storeL(sH1[0], a1);   // h1(0)
        bmPrev = bmIn;
        __syncthreads();
    }

    // ---- main: i = 2..127, one barrier per iteration ----
    auto stepMain = [&](int i, const short* r0, const short* r1,
                        short* w0b, short* w1b) {
        const bool bmIn = (sMask[i - 1] >> c) & 1u;
        const float* bp = bmIn ? (sBias + 128) : sBias;
        f32x4 a0 = *reinterpret_cast<const f32x4*>(&bp[ib]);
        f32x4 a1 = *reinterpret_cast<const f32x4*>(&sBias[256 + ib]);
        bf16x8 f0[4], f1[4];
        #pragma unroll
        for (int kb = 0; kb < 4; ++kb) {
            f0[kb] = *reinterpret_cast<const bf16x8*>(&r0[ra[kb]]);
            f1[kb] = *reinterpret_cast<const bf16x8*>(&r1[ra[kb]]);
        }
        __builtin_amdgcn_s_setprio(1);
        #pragma unroll
        for (int kb = 0; kb < 4; ++kb) {
            a0 = __builtin_amdgcn_mfma_f32_16x16x32_bf16(fhh0[kb], f0[kb], a0, 0, 0, 0);
            a1 = __builtin_amdgcn_mfma_f32_16x16x32_bf16(fhh1[kb], f1[kb], a1, 0, 0, 0);
        }
        #pragma unroll
        for (int kb = 0; kb < 4; ++kb)
            a1 = __builtin_amdgcn_mfma_f32_16x16x32_bf16(fih1[kb], f0[kb], a1, 0, 0, 0);
        __builtin_amdgcn_s_setprio(0);
        // 4-way logit duty: waves {i, i+2, i+4, i+6} & 7, one kb each
        const int dk = (w - i) & 7;
        if (!(dk & 1)) {
            const int kpart = dk >> 1;
            f32x4 aL = (kpart == 0) ? (f32x4){bd0, bd1, 0.f, 0.f}
                                    : (f32x4){0.f, 0.f, 0.f, 0.f};
            bf16x8 fw = *reinterpret_cast<const bf16x8*>(&sFwd[(kpart * 64 + lane) * 8]);
            aL = __builtin_amdgcn_mfma_f32_16x16x32_bf16(fw, f1[kpart], aL, 0, 0, 0);
            if (q == 0)
                sLd[((i - 2) * 4 + kpart) * 17 + c] =
                    bmPrev ? (aL[0] - aL[1]) : (aL[1] - aL[0]);
        }
        bmPrev = bmIn;
        storeL(w0b, a0);              // h0(i)
        storeL(w1b, a1);              // h1(i-1)
        __syncthreads();
    };

    for (int i = 2; i < NSTEP; i += 2) {
        stepMain(i,     sH0[0], sH1[0], sH0[1], sH1[1]);
        stepMain(i + 1, sH0[1], sH1[1], sH0[0], sH1[0]);
    }

    // ---- i = 128: h1(127), logits(126) ----
    {
        f32x4 a1 = *reinterpret_cast<const f32x4*>(&sBias[256 + ib]);
        bf16x8 f0[4], f1[4];
        #pragma unroll
        for (int kb = 0; kb < 4; ++kb) {
            f0[kb] = *reinterpret_cast<const bf16x8*>(&sH0[0][ra[kb]]);  // h0(127)
            f1[kb] = *reinterpret_cast<const bf16x8*>(&sH1[0][ra[kb]]);  // h1(126)
        }
        #pragma unroll
        for (int kb = 0; kb < 4; ++kb)
            a1 = __builtin_amdgcn_mfma_f32_16x16x32_bf16(fhh1[kb], f1[kb], a1, 0, 0, 0);
        #pragma unroll
        for (int kb = 0; kb < 4; ++kb)
            a1 = __builtin_amdgcn_mfma_f32_16x16x32_bf16(fih1[kb], f0[kb], a1, 0, 0, 0);
        const int dk = (w - 128) & 7;   // waves 0,2,4,6
        if (!(dk & 1)) {
            const int kpart = dk >> 1;
            f32x4 aL = (kpart == 0) ? (f32x4){bd0, bd1, 0.f, 0.f}
                                    : (f32x4){0.f, 0.f, 0.f, 0.f};
            bf16x8 fw = *reinterpret_cast<const bf16x8*>(&sFwd[(kpart * 64 + lane) * 8]);
            aL = __builtin_amdgcn_mfma_f32_16x16x32_bf16(fw, f1[kpart], aL, 0, 0, 0);
            if (q == 0)
                sLd[(126 * 4 + kpart) * 17 + c] =
                    bmPrev ? (aL[0] - aL[1]) : (aL[1] - aL[0]);
        }
        storeL(sH1[1], a1);           // h1(127)
        __syncthreads();
    }
    // ---- i = 129: logits(127), waves 1,3,5,7 ----
    {
        const int dk = (w - 129) & 7;
        if (!(dk & 1)) {
            const int kpart = dk >> 1;
            bf16x8 f1v = *reinterpret_cast<const bf16x8*>(&sH1[1][ra[kpart]]);
            bf16x8 fw  = *reinterpret_cast<const bf16x8*>(&sFwd[(kpart * 64 + lane) * 8]);
            f32x4 aL = (kpart == 0) ? (f32x4){bd0, bd1, 0.f, 0.f}
                                    : (f32x4){0.f, 0.f, 0.f, 0.f};
            aL = __builtin_amdgcn_mfma_f32_16x16x32_bf16(fw, f1v, aL, 0, 0, 0);
            if (q == 0) {
                const bool bit = (sMask[NSTEP - 1] >> c) & 1u;
                sLd[(127 * 4 + kpart) * 17 + c] =
                    bit ? (aL[0] - aL[1]) : (aL[1] - aL[0]);
            }
        }
    }
    __syncthreads();

    // ---- final pass: lp(s) = sum_t -log(1 + exp(sum_k diff_part)) ----
    if (tid < 256) {
        const int s = tid >> 4;       // sample 0..15
        const int k = tid & 15;       // step sub-index
        float acc = 0.0f;
        #pragma unroll
        for (int j = 0; j < 8; ++j) {
            const int base = (j * 16 + k) * 68 + s;   // (t*4+0)*17 + s
            const float x = sLd[base] + sLd[base + 17]
                          + sLd[base + 34] + sLd[base + 51];
            const float ed = __builtin_exp2f(x * 1.4426950408889634f);
            acc -= 0.6931471805599453f * __builtin_log2f(1.0f + ed);
        }
        #pragma unroll
        for (int off = 1; off < 16; off <<= 1)
            acc += __shfl_xor(acc, off, 64);
        if (k == 0)
            out[b0 + s] = acc;
    }
}

extern "C" void kernel_launch(void* const* d_in, const int* in_sizes, int n_in,
                              void* d_out, int out_size, void* d_ws, size_t ws_size,
                              hipStream_t stream) {
    rnn_wf_kernel<<<NBLK, NTHR, 0, stream>>>(
        (const float*)d_in[0],  // samples
        (const float*)d_in[1],  // W_ih0
        (const float*)d_in[2],  // b_ih0
        (const float*)d_in[3],  // W_hh0
        (const float*)d_in[4],  // b_hh0
        (const float*)d_in[5],  // W_ih1
        (const float*)d_in[6],  // b_ih1
        (const float*)d_in[7],  // W_hh1
        (const float*)d_in[8],  // b_hh1
        (const float*)d_in[9],  // W_dense
        (const float*)d_in[10], // b_dense
        (float*)d_out);
}

// Round 7
// 251.478 us; speedup vs baseline: 2.1853x; 2.1853x over previous
//
#include <hip/hip_runtime.h>
#include <hip/hip_bf16.h>

// RNN wavefunction log-prob: N=128 steps, B=8192, H=128, D=2 (one-hot).
// R14: tile-fusion for intra-wave ILP. Evidence: no pipe saturated at R7
// (LDS ~48%, VALU ~55%, MFMA 23%) and per-wave ILP is nearly free (R9),
// but block residency is reg-capped at 2 (R11). So: fuse TWO independent
// 16-sample tiles per block (256 blocks x 512 thr, 32 samples), sharing
// the register-resident weights. Exact R7 body duplicated with A/B
// suffixes -- no runtime-indexed reg arrays (R13 lesson), no setprio,
// biases in LDS (R8 lesson). launch_bounds(512,2) -> 256-reg budget.

#define NSTEP 128
#define BTOT  8192
#define HID   128
#define SPB   32            // samples per block (two 16-wide tiles)
#define NBLK  (BTOT / SPB)  // 256
#define NTHR  512

typedef __attribute__((ext_vector_type(8))) short bf16x8;
typedef __attribute__((ext_vector_type(4))) float f32x4;
typedef __attribute__((ext_vector_type(2))) float f32x2;
typedef __attribute__((ext_vector_type(2))) unsigned uint32x2;

__device__ __forceinline__ short f2bf(float v) {
    unsigned u = __builtin_bit_cast(unsigned, v);
    u += 0x7FFFu + ((u >> 16) & 1u);
    return (short)(u >> 16);
}
// two f32 -> packed bf16x2 via v_cvt_pk_bf16_f32
__device__ __forceinline__ unsigned cvt2bf(float a, float b) {
    __hip_bfloat162 h2 = __float22bfloat162_rn(make_float2(a, b));
    unsigned u; __builtin_memcpy(&u, &h2, sizeof(u));
    return u;
}
// tanh on a pair: 2 exp + ONE rcp (shared via rcp(d0*d1))
__device__ __forceinline__ f32x2 tanh2(f32x2 x) {
    f32x2 z = x * 2.885390081777927f;            // 2x*log2(e)
    float e0 = __builtin_exp2f(z.x);
    float e1 = __builtin_exp2f(z.y);
    f32x2 d = {e0 + 1.0f, e1 + 1.0f};
    float r = __builtin_amdgcn_rcpf(d.x * d.y);
    f32x2 inv = {r * d.y, r * d.x};              // 1/d.x, 1/d.y
    return inv * -2.0f + 1.0f;
}

__global__ __launch_bounds__(NTHR, 2) void rnn_wf_kernel(
    const float* __restrict__ samples,  // (128, 8192, 2)
    const float* __restrict__ Wih0,     // (128, 2)
    const float* __restrict__ bih0,     // (128,)
    const float* __restrict__ Whh0,     // (128, 128)
    const float* __restrict__ bhh0,     // (128,)
    const float* __restrict__ Wih1,     // (128, 128)
    const float* __restrict__ bih1,     // (128,)
    const float* __restrict__ Whh1,     // (128, 128)
    const float* __restrict__ bhh1,     // (128,)
    const float* __restrict__ Wd,       // (2, 128)
    const float* __restrict__ bd,       // (2,)
    float* __restrict__ out)            // (1, 8192)
{
    __shared__ short sH0A[2][16 * HID];
    __shared__ short sH1A[2][16 * HID];
    __shared__ short sH0B[2][16 * HID];
    __shared__ short sH1B[2][16 * HID];
    __shared__ unsigned sMask[NSTEP];            // bits 0-15 tile A, 16-31 tile B
    __shared__ float sLd[2][NSTEP * 17];         // logit diffs per tile
    __shared__ __attribute__((aligned(16))) float sBias[4 * HID];
    // segments: [0:128)=WA (b0+Wih0 col0), [128:256)=WB (col1),
    //           [256:384)=B1, [384:512)=B0 plain
    __shared__ __attribute__((aligned(16))) short sFwd[4 * 64 * 8];

    const int tid  = threadIdx.x;
    const int b0   = blockIdx.x * SPB;
    const int w    = tid >> 6;          // wave 0..7, owns n in [16w, 16w+16)
    const int lane = tid & 63;
    const int q    = lane >> 4;
    const int c    = lane & 15;

    // ---- decode f32 one-hot samples -> per-step 32-bit masks ----
    if (tid < NSTEP) {
        unsigned msk = 0;
        #pragma unroll
        for (int m = 0; m < SPB; ++m) {
            float e1 = samples[((size_t)tid * BTOT + b0 + m) * 2 + 1];
            if (e1 > 0.5f) msk |= (1u << m);
        }
        sMask[tid] = msk;
    }
    // ---- biases into LDS ----
    if (tid >= NSTEP && tid < NSTEP + HID) {
        const int n = tid - NSTEP;
        const float bb = bih0[n] + bhh0[n];
        sBias[n]       = bb + Wih0[n * 2 + 0];
        sBias[128 + n] = bb + Wih0[n * 2 + 1];
        sBias[256 + n] = bih1[n] + bhh1[n];
        sBias[384 + n] = bb;
    }
    // ---- dense-head fragments into LDS ----
    if (tid >= 256 && tid < 512) {
        const int t2 = tid - 256;
        const int kb = t2 >> 6, l = t2 & 63, cc = l & 15, qq = l >> 4;
        bf16x8 v;
        #pragma unroll
        for (int j = 0; j < 8; ++j)
            v[j] = (cc < 2) ? f2bf(Wd[cc * HID + kb * 32 + qq * 8 + j]) : (short)0;
        *reinterpret_cast<bf16x8*>(&sFwd[(kb * 64 + l) * 8]) = v;
    }

    // ---- weight A-fragments: lane holds W[16w+c][kb*32+q*8 .. +8] ----
    bf16x8 fhh0[4], fih1[4], fhh1[4];
    {
        const int nn = w * 16 + c;
        #pragma unroll
        for (int kb = 0; kb < 4; ++kb) {
            const int off = nn * HID + kb * 32 + q * 8;
            bf16x8 v0, v1, v2;
            #pragma unroll
            for (int j = 0; j < 8; ++j) {
                v0[j] = f2bf(Whh0[off + j]);
                v1[j] = f2bf(Wih1[off + j]);
                v2[j] = f2bf(Whh1[off + j]);
            }
            fhh0[kb] = v0; fih1[kb] = v1; fhh1[kb] = v2;
        }
    }
    const float bd0 = bd[0], bd1 = bd[1];

    // ---- t-invariant LDS indices ----
    int ra[4];
    #pragma unroll
    for (int kb = 0; kb < 4; ++kb)
        ra[kb] = c * HID + (((kb * 4 + q) ^ c) << 3);
    // write: h'[m=c][n = 16w + 4q + r]; 8-block = 2w + (q>>1), half q&1
    const int wa = c * HID + (((2 * w + (q >> 1)) ^ c) << 3) + ((q & 1) << 2);
    const int ib = w * 16 + q * 4;   // float index into bias arrays

    bool bmPrevA = false, bmPrevB = false;

    // write one layer's 4 tanh'd values (b64)
    auto storeL = [&](short* buf, const f32x4& a) {
        f32x2 t0 = tanh2((f32x2){a[0], a[1]});
        f32x2 t1 = tanh2((f32x2){a[2], a[3]});
        uint32x2 v = {cvt2bf(t0.x, t0.y), cvt2bf(t1.x, t1.y)};
        *reinterpret_cast<uint32x2*>(&buf[wa]) = v;
    };

    __syncthreads();                 // sMask, sBias, sFwd published

    // ---- i = 0: h0(0) = tanh(b0), both tiles ----
    {
        f32x4 bv = *reinterpret_cast<const f32x4*>(&sBias[384 + ib]);
        storeL(sH0A[1], bv);
        storeL(sH0B[1], bv);
    }
    __syncthreads();

    // ---- i = 1: h0(1), h1(0), both tiles ----
    {
        const unsigned msk = sMask[0];
        const bool bmA = (msk >> c) & 1u;
        const bool bmB = (msk >> (16 + c)) & 1u;
        const float* bpA = bmA ? (sBias + 128) : sBias;
        const float* bpB = bmB ? (sBias + 128) : sBias;
        f32x4 a0A = *reinterpret_cast<const f32x4*>(&bpA[ib]);
        f32x4 a0B = *reinterpret_cast<const f32x4*>(&bpB[ib]);
        f32x4 a1A = *reinterpret_cast<const f32x4*>(&sBias[256 + ib]);
        f32x4 a1B = a1A;
        #pragma unroll
        for (int kb = 0; kb < 4; ++kb) {
            bf16x8 f0A = *reinterpret_cast<const bf16x8*>(&sH0A[1][ra[kb]]);
            bf16x8 f0B = *reinterpret_cast<const bf16x8*>(&sH0B[1][ra[kb]]);
            a0A = __builtin_amdgcn_mfma_f32_16x16x32_bf16(fhh0[kb], f0A, a0A, 0, 0, 0);
            a0B = __builtin_amdgcn_mfma_f32_16x16x32_bf16(fhh0[kb], f0B, a0B, 0, 0, 0);
            a1A = __builtin_amdgcn_mfma_f32_16x16x32_bf16(fih1[kb], f0A, a1A, 0, 0, 0);
            a1B = __builtin_amdgcn_mfma_f32_16x16x32_bf16(fih1[kb], f0B, a1B, 0, 0, 0);
        }
        storeL(sH0A[0], a0A);   // h0(1)
        storeL(sH1A[0], a1A);   // h1(0)
        storeL(sH0B[0], a0B);
        storeL(sH1B[0], a1B);
        bmPrevA = bmA; bmPrevB = bmB;
        __syncthreads();
    }

    // ---- main: i = 2..127, one barrier per iteration, both tiles ----
    auto stepMain = [&](int i,
                        const short* r0A, const short* r1A, short* w0A, short* w1A,
                        const short* r0B, const short* r1B, short* w0B, short* w1B) {
        const unsigned msk = sMask[i - 1];
        const bool bmA = (msk >> c) & 1u;
        const bool bmB = (msk >> (16 + c)) & 1u;
        const float* bpA = bmA ? (sBias + 128) : sBias;
        const float* bpB = bmB ? (sBias + 128) : sBias;
        f32x4 a0A = *reinterpret_cast<const f32x4*>(&bpA[ib]);
        f32x4 a0B = *reinterpret_cast<const f32x4*>(&bpB[ib]);
        f32x4 a1A = *reinterpret_cast<const f32x4*>(&sBias[256 + ib]);
        f32x4 a1B = a1A;
        bf16x8 f0A[4], f1A[4], f0B[4], f1B[4];
        #pragma unroll
        for (int kb = 0; kb < 4; ++kb) {
            f0A[kb] = *reinterpret_cast<const bf16x8*>(&r0A[ra[kb]]);
            f1A[kb] = *reinterpret_cast<const bf16x8*>(&r1A[ra[kb]]);
            f0B[kb] = *reinterpret_cast<const bf16x8*>(&r0B[ra[kb]]);
            f1B[kb] = *reinterpret_cast<const bf16x8*>(&r1B[ra[kb]]);
        }
        #pragma unroll
        for (int kb = 0; kb < 4; ++kb) {
            a0A = __builtin_amdgcn_mfma_f32_16x16x32_bf16(fhh0[kb], f0A[kb], a0A, 0, 0, 0);
            a0B = __builtin_amdgcn_mfma_f32_16x16x32_bf16(fhh0[kb], f0B[kb], a0B, 0, 0, 0);
            a1A = __builtin_amdgcn_mfma_f32_16x16x32_bf16(fhh1[kb], f1A[kb], a1A, 0, 0, 0);
            a1B = __builtin_amdgcn_mfma_f32_16x16x32_bf16(fhh1[kb], f1B[kb], a1B, 0, 0, 0);
        }
        #pragma unroll
        for (int kb = 0; kb < 4; ++kb) {
            a1A = __builtin_amdgcn_mfma_f32_16x16x32_bf16(fih1[kb], f0A[kb], a1A, 0, 0, 0);
            a1B = __builtin_amdgcn_mfma_f32_16x16x32_bf16(fih1[kb], f0B[kb], a1B, 0, 0, 0);
        }
        if (w == (i & 7)) {          // tile-A logits duty
            f32x4 aL = {bd0, bd1, 0.f, 0.f};
            #pragma unroll
            for (int kb = 0; kb < 4; ++kb) {
                bf16x8 fw = *reinterpret_cast<const bf16x8*>(&sFwd[(kb * 64 + lane) * 8]);
                aL = __builtin_amdgcn_mfma_f32_16x16x32_bf16(fw, f1A[kb], aL, 0, 0, 0);
            }
            if (q == 0)
                sLd[0][(i - 2) * 17 + c] = bmPrevA ? (aL[0] - aL[1]) : (aL[1] - aL[0]);
        }
        if (w == ((i + 4) & 7)) {    // tile-B logits duty
            f32x4 aL = {bd0, bd1, 0.f, 0.f};
            #pragma unroll
            for (int kb = 0; kb < 4; ++kb) {
                bf16x8 fw = *reinterpret_cast<const bf16x8*>(&sFwd[(kb * 64 + lane) * 8]);
                aL = __builtin_amdgcn_mfma_f32_16x16x32_bf16(fw, f1B[kb], aL, 0, 0, 0);
            }
            if (q == 0)
                sLd[1][(i - 2) * 17 + c] = bmPrevB ? (aL[0] - aL[1]) : (aL[1] - aL[0]);
        }
        bmPrevA = bmA; bmPrevB = bmB;
        storeL(w0A, a0A);            // h0(i)
        storeL(w1A, a1A);            // h1(i-1)
        storeL(w0B, a0B);
        storeL(w1B, a1B);
        __syncthreads();
    };

    for (int i = 2; i < NSTEP; i += 2) {
        stepMain(i,
                 sH0A[0], sH1A[0], sH0A[1], sH1A[1],
                 sH0B[0], sH1B[0], sH0B[1], sH1B[1]);
        stepMain(i + 1,
                 sH0A[1], sH1A[1], sH0A[0], sH1A[0],
                 sH0B[1], sH1B[1], sH0B[0], sH1B[0]);
    }

    // ---- i = 128: h1(127), logits(126), both tiles ----
    {
        f32x4 a1A = *reinterpret_cast<const f32x4*>(&sBias[256 + ib]);
        f32x4 a1B = a1A;
        bf16x8 f0A[4], f1A[4], f0B[4], f1B[4];
        #pragma unroll
        for (int kb = 0; kb < 4; ++kb) {
            f0A[kb] = *reinterpret_cast<const bf16x8*>(&sH0A[0][ra[kb]]);  // h0(127)
            f1A[kb] = *reinterpret_cast<const bf16x8*>(&sH1A[0][ra[kb]]);  // h1(126)
            f0B[kb] = *reinterpret_cast<const bf16x8*>(&sH0B[0][ra[kb]]);
            f1B[kb] = *reinterpret_cast<const bf16x8*>(&sH1B[0][ra[kb]]);
        }
        #pragma unroll
        for (int kb = 0; kb < 4; ++kb) {
            a1A = __builtin_amdgcn_mfma_f32_16x16x32_bf16(fhh1[kb], f1A[kb], a1A, 0, 0, 0);
            a1B = __builtin_amdgcn_mfma_f32_16x16x32_bf16(fhh1[kb], f1B[kb], a1B, 0, 0, 0);
        }
        #pragma unroll
        for (int kb = 0; kb < 4; ++kb) {
            a1A = __builtin_amdgcn_mfma_f32_16x16x32_bf16(fih1[kb], f0A[kb], a1A, 0, 0, 0);
            a1B = __builtin_amdgcn_mfma_f32_16x16x32_bf16(fih1[kb], f0B[kb], a1B, 0, 0, 0);
        }
        if (w == 0) {                // 128 & 7 == 0
            f32x4 aL = {bd0, bd1, 0.f, 0.f};
            #pragma unroll
            for (int kb = 0; kb < 4; ++kb) {
                bf16x8 fw = *reinterpret_cast<const bf16x8*>(&sFwd[(kb * 64 + lane) * 8]);
                aL = __builtin_amdgcn_mfma_f32_16x16x32_bf16(fw, f1A[kb], aL, 0, 0, 0);
            }
            if (q == 0)
                sLd[0][126 * 17 + c] = bmPrevA ? (aL[0] - aL[1]) : (aL[1] - aL[0]);
        }
        if (w == 4) {                // (128+4) & 7 == 4
            f32x4 aL = {bd0, bd1, 0.f, 0.f};
            #pragma unroll
            for (int kb = 0; kb < 4; ++kb) {
                bf16x8 fw = *reinterpret_cast<const bf16x8*>(&sFwd[(kb * 64 + lane) * 8]);
                aL = __builtin_amdgcn_mfma_f32_16x16x32_bf16(fw, f1B[kb], aL, 0, 0, 0);
            }
            if (q == 0)
                sLd[1][126 * 17 + c] = bmPrevB ? (aL[0] - aL[1]) : (aL[1] - aL[0]);
        }
        storeL(sH1A[1], a1A);        // h1(127)
        storeL(sH1B[1], a1B);
        __syncthreads();
    }
    // ---- i = 129: logits(127), waves 1 (A) and 5 (B) ----
    if (w == 1) {
        f32x4 aL = {bd0, bd1, 0.f, 0.f};
        #pragma unroll
        for (int kb = 0; kb < 4; ++kb) {
            bf16x8 f1 = *reinterpret_cast<const bf16x8*>(&sH1A[1][ra[kb]]);
            bf16x8 fw = *reinterpret_cast<const bf16x8*>(&sFwd[(kb * 64 + lane) * 8]);
            aL = __builtin_amdgcn_mfma_f32_16x16x32_bf16(fw, f1, aL, 0, 0, 0);
        }
        if (q == 0) {
            const bool bit = (sMask[NSTEP - 1] >> c) & 1u;
            sLd[0][127 * 17 + c] = bit ? (aL[0] - aL[1]) : (aL[1] - aL[0]);
        }
    }
    if (w == 5) {
        f32x4 aL = {bd0, bd1, 0.f, 0.f};
        #pragma unroll
        for (int kb = 0; kb < 4; ++kb) {
            bf16x8 f1 = *reinterpret_cast<const bf16x8*>(&sH1B[1][ra[kb]]);
            bf16x8 fw = *reinterpret_cast<const bf16x8*>(&sFwd[(kb * 64 + lane) * 8]);
            aL = __builtin_amdgcn_mfma_f32_16x16x32_bf16(fw, f1, aL, 0, 0, 0);
        }
        if (q == 0) {
            const bool bit = (sMask[NSTEP - 1] >> (16 + c)) & 1u;
            sLd[1][127 * 17 + c] = bit ? (aL[0] - aL[1]) : (aL[1] - aL[0]);
        }
    }
    __syncthreads();

    // ---- final pass: lp(s) = sum_t -log(1 + exp(diff_t)) ----
    {
        const int s  = tid >> 4;      // sample 0..31
        const int k  = tid & 15;      // step sub-index
        const int tb = s >> 4;        // tile 0/1
        const int si = s & 15;        // sample within tile
        float acc = 0.0f;
        #pragma unroll
        for (int j = 0; j < 8; ++j) {
            const float x = sLd[tb][(j * 16 + k) * 17 + si];
            const float ed = __builtin_exp2f(x * 1.4426950408889634f);
            acc -= 0.6931471805599453f * __builtin_log2f(1.0f + ed);
        }
        #pragma unroll
        for (int off = 1; off < 16; off <<= 1)
            acc += __shfl_xor(acc, off, 64);
        if (k == 0)
            out[b0 + s] = acc;
    }
}

extern "C" void kernel_launch(void* const* d_in, const int* in_sizes, int n_in,
                              void* d_out, int out_size, void* d_ws, size_t ws_size,
                              hipStream_t stream) {
    rnn_wf_kernel<<<NBLK, NTHR, 0, stream>>>(
        (const float*)d_in[0],  // samples
        (const float*)d_in[1],  // W_ih0
        (const float*)d_in[2],  // b_ih0
        (const float*)d_in[3],  // W_hh0
        (const float*)d_in[4],  // b_hh0
        (const float*)d_in[5],  // W_ih1
        (const float*)d_in[6],  // b_ih1
        (const float*)d_in[7],  // W_hh1
        (const float*)d_in[8],  // b_hh1
        (const float*)d_in[9],  // W_dense
        (const float*)d_in[10], // b_dense
        (float*)d_out);
}